// Round 5
// baseline (23467.102 us; speedup 1.0000x reference)
//
#include <hip/hip_runtime.h>
#include <math.h>
#include <stdint.h>

// Problem constants
constexpr int LL = 4096;   // seq len
constexpr int EE = 300;    // embedding dim
constexpr int HH = 256;    // per-direction hidden (H2)
constexpr int NGATE = 1024;// 4*HH
constexpr int TT = 16;     // tagset
constexpr float NEGV = -10000.0f;

typedef _Float16 v2h __attribute__((ext_vector_type(2)));
typedef _Float16 v8h __attribute__((ext_vector_type(8)));
typedef float v4f __attribute__((ext_vector_type(4)));

// Workspace layout (byte offsets)
constexpr size_t OFF_X    = 16384;
constexpr size_t OFF_ZX   = OFF_X    + (size_t)LL*EE*4;     // 2*L*1024 f32
constexpr size_t OFF_HALL = OFF_ZX   + (size_t)2*LL*NGATE*4;// 2*L*256 f32
constexpr size_t OFF_FE   = OFF_HALL + (size_t)2*LL*HH*4;   // L*16 f32

__device__ __forceinline__ v2h pack_h2(float x, float y) {
  return __builtin_bit_cast(v2h, __builtin_amdgcn_cvt_pkrtz(x, y));
}
__device__ __forceinline__ unsigned pack_u(float x, float y) {
  return __builtin_bit_cast(unsigned, __builtin_amdgcn_cvt_pkrtz(x, y));
}
__device__ __forceinline__ v2h u2h(unsigned u) {
  return __builtin_bit_cast(v2h, u);
}
__device__ __forceinline__ v8h make_v8h(v2h a, v2h b, v2h c, v2h d) {
  union { v2h p[4]; v8h v; } u; u.p[0]=a; u.p[1]=b; u.p[2]=c; u.p[3]=d; return u.v;
}

__device__ __forceinline__ float fsigmoid(float x) {
  return __builtin_amdgcn_rcpf(1.f + __expf(-x));
}
__device__ __forceinline__ float ftanh(float x) {
  return 1.f - 2.f * __builtin_amdgcn_rcpf(1.f + __expf(2.f * x));
}

template <int CTRL>
__device__ __forceinline__ int dpp_i(int v) {
  return __builtin_amdgcn_mov_dpp(v, CTRL, 0xF, 0xF, true);
}
template <int CTRL>
__device__ __forceinline__ float dpp_f(float v) {
  return __int_as_float(__builtin_amdgcn_mov_dpp(__float_as_int(v), CTRL, 0xF, 0xF, true));
}
__device__ __forceinline__ float bperm_f(int lane, float v) {
  return __int_as_float(__builtin_amdgcn_ds_bpermute(lane << 2, __float_as_int(v)));
}

// ---------------------------------------------------------------------------
// Kernel 1: embedding gather
// ---------------------------------------------------------------------------
__global__ void gather_x(const int* __restrict__ sent, const float* __restrict__ emb,
                         float* __restrict__ X) {
  const int i = blockIdx.x * blockDim.x + threadIdx.x;
  const int total = LL * (EE / 4);
  if (i >= total) return;
  const int row = i / (EE / 4), c4 = i % (EE / 4);
  const int v = sent[row];
  reinterpret_cast<float4*>(X)[(size_t)row * (EE / 4) + c4] =
      reinterpret_cast<const float4*>(emb + (size_t)v * EE)[c4];
}

// ---------------------------------------------------------------------------
// Kernel 2: input GEMM  Zx[dir][t][u][g] = X[t]·W_ih[g*256+u] + b  (GATE-
// TRANSPOSED store: row layout [unit][gate] so recurrence reads one float4)
// ---------------------------------------------------------------------------
__global__ __launch_bounds__(256) void input_gemm(
    const float* __restrict__ X, const float* __restrict__ w_f,
    const float* __restrict__ b_f, const float* __restrict__ w_b,
    const float* __restrict__ b_b, float* __restrict__ ZX) {
  const int dir = blockIdx.z;
  const float* __restrict__ W  = dir ? w_b : w_f;
  const float* __restrict__ Bv = dir ? b_b : b_f;
  float* __restrict__ Z = ZX + (size_t)dir * LL * NGATE;
  __shared__ float As[32][68];
  __shared__ float Bs[32][68];
  const int m0 = blockIdx.y * 64, n0 = blockIdx.x * 64;
  const int t = threadIdx.x;
  const int tx = t & 15, ty = t >> 4;
  float acc[4][4] = {};
  for (int k0 = 0; k0 < EE; k0 += 32) {
#pragma unroll
    for (int r = 0; r < 2; ++r) {
      const int idx = t + r * 256;
      const int row = idx >> 3;
      const int kk4 = (idx & 7) << 2;
      const int k = k0 + kk4;
      float4 va = make_float4(0.f, 0.f, 0.f, 0.f), vb = va;
      if (k < EE) {
        va = *reinterpret_cast<const float4*>(X + (size_t)(m0 + row) * EE + k);
        vb = *reinterpret_cast<const float4*>(W + (size_t)(n0 + row) * EE + k);
      }
      As[kk4 + 0][row] = va.x; As[kk4 + 1][row] = va.y;
      As[kk4 + 2][row] = va.z; As[kk4 + 3][row] = va.w;
      Bs[kk4 + 0][row] = vb.x; Bs[kk4 + 1][row] = vb.y;
      Bs[kk4 + 2][row] = vb.z; Bs[kk4 + 3][row] = vb.w;
    }
    __syncthreads();
    const int kmax = (EE - k0 < 32) ? (EE - k0) : 32;
    for (int k = 0; k < kmax; ++k) {
      const float4 av = *reinterpret_cast<const float4*>(&As[k][ty << 2]);
      const float4 bv = *reinterpret_cast<const float4*>(&Bs[k][tx << 2]);
      acc[0][0] += av.x * bv.x; acc[0][1] += av.x * bv.y; acc[0][2] += av.x * bv.z; acc[0][3] += av.x * bv.w;
      acc[1][0] += av.y * bv.x; acc[1][1] += av.y * bv.y; acc[1][2] += av.y * bv.z; acc[1][3] += av.y * bv.w;
      acc[2][0] += av.z * bv.x; acc[2][1] += av.z * bv.y; acc[2][2] += av.z * bv.z; acc[2][3] += av.z * bv.w;
      acc[3][0] += av.w * bv.x; acc[3][1] += av.w * bv.y; acc[3][2] += av.w * bv.z; acc[3][3] += av.w * bv.w;
    }
    __syncthreads();
  }
#pragma unroll
  for (int i = 0; i < 4; ++i)
#pragma unroll
    for (int j = 0; j < 4; ++j) {
      const int m = m0 + (ty << 2) + i, n = n0 + (tx << 2) + j;
      // gate-transposed: addr = unit*4 + gate
      Z[(size_t)m * NGATE + (((n & 255) << 2) | (n >> 8))] = acc[i][j] + Bv[n];
    }
}

// ---------------------------------------------------------------------------
// Kernel 3: persistent bidirectional LSTM recurrence — one WG per direction.
//
// R3 post-mortem: all three prior structures were issue-bound on
// v_accvgpr_read/write traffic: with waves_per_eu(2,2) the unified file is
// 256 regs/thread and the backend splits it 128 arch / 128 acc (VGPR_Count
// =128 every round). Any design demanding >128 ARCH regs gets its fdot2
// weights stashed in AGPRs with a VALU move per use (~1600 cy/step).
// R4: budget TO the split.
//   arch (<=~128): wv[3][32]=96 f16-pair weights -> VALU covers n in [0,384)
//   acc  (96):     bfr[24] MFMA B-frags (MFMA reads AGPR natively, 0 moves)
//                  -> reg-MFMA covers n in [384,768), tiles 24+3w+i
//   LDS  (128 KB): 16 B-frag tiles -> streamed MFMA covers n in [768,1024),
//                  tiles 48+2w+i (b128, 2-way free)
// kc-outer passes so the A-frag (h, replicated rows — R2/R3-verified) is
// read once per kc per pass. z and Zx are gate-transposed: gate phase does
// ONE float4 LDS read + ONE float4 global prefetch.
// Pipes/step/CU: MFMA 40 tiles*8*4.85 = 1552 cy; LDS 128 KB ~1500 cy;
// VALU ~700 cy — concurrent (m114) -> ~1800-2100 cy vs 3650 measured.
// (R4 bench was an infra failure — "container failed twice", never ran.
//  Code re-audited: transpose maps, k-pairing, races, reg budget all check.
//  Resubmitted unchanged.)
// ---------------------------------------------------------------------------
__global__ __launch_bounds__(512) __attribute__((amdgpu_waves_per_eu(2, 2)))
void recurrence(
    const float* __restrict__ whh_f, const float* __restrict__ whh_b,
    const float* __restrict__ h0, const float* __restrict__ c0,
    const float* __restrict__ ZX, float* __restrict__ HALL) {
  const int dir = blockIdx.x;
  const int t = threadIdx.x;
  const int w = t >> 6;            // wave 0..7
  const int l = t & 63;
  const int lcol = l & 15;
  const int lq = l >> 4;           // quadrant 0..3
  const int rq = t >> 2;           // 0..127 (VALU row group)
  const int kq = t & 3;            // VALU k-quarter
  const float* __restrict__ Whh = dir ? whh_b : whh_f;
  const float* __restrict__ Z = ZX + (size_t)dir * LL * NGATE;
  float* __restrict__ Hall = HALL + (size_t)dir * LL * HH;

  __shared__ uint4 WL[16 * 8 * 64];                 // 128 KB streamed B-frags
  __shared__ __align__(16) float zbuf4[NGATE];      // 4 KB, [unit][gate]
  __shared__ __align__(16) unsigned h16u[2 * 128];  // packed f16 h, parity dbuf

  // ---- preamble 1: VALU weights (n in [0,384)) -> 96 arch VGPRs ----------
  v2h wv[3][32];
#pragma unroll
  for (int j = 0; j < 3; ++j) {
    const float* wr = Whh + (size_t)(rq + (j << 7)) * HH + (kq << 6);
#pragma unroll
    for (int i = 0; i < 8; ++i) {
      const float4 x = *reinterpret_cast<const float4*>(wr + 8 * i);
      const float4 y = *reinterpret_cast<const float4*>(wr + 8 * i + 4);
      wv[j][4 * i + 0] = pack_h2(x.x, x.y);
      wv[j][4 * i + 1] = pack_h2(x.z, x.w);
      wv[j][4 * i + 2] = pack_h2(y.x, y.y);
      wv[j][4 * i + 3] = pack_h2(y.z, y.w);
    }
  }

  // ---- preamble 2: reg-resident MFMA B-frags (tiles 24+3w+i) -------------
  v8h bfr[24];
#pragma unroll
  for (int i = 0; i < 3; ++i)
#pragma unroll
    for (int kc = 0; kc < 8; ++kc) {
      const int n = ((24 + 3 * w + i) << 4) + lcol;
      const float* wp = Whh + (size_t)n * HH + (kc << 5) + (lq << 3);
      const float4 a4 = *reinterpret_cast<const float4*>(wp);
      const float4 b4 = *reinterpret_cast<const float4*>(wp + 4);
      bfr[i * 8 + kc] = make_v8h(pack_h2(a4.x, a4.y), pack_h2(a4.z, a4.w),
                                 pack_h2(b4.x, b4.y), pack_h2(b4.z, b4.w));
    }

  // ---- preamble 3: LDS-streamed MFMA B-frags (tiles 48+2w+i) -------------
#pragma unroll
  for (int i = 0; i < 2; ++i)
#pragma unroll
    for (int kc = 0; kc < 8; ++kc) {
      const int n = ((48 + 2 * w + i) << 4) + lcol;
      const float* wp = Whh + (size_t)n * HH + (kc << 5) + (lq << 3);
      const float4 a4 = *reinterpret_cast<const float4*>(wp);
      const float4 b4 = *reinterpret_cast<const float4*>(wp + 4);
      uint4 p;
      p.x = pack_u(a4.x, a4.y); p.y = pack_u(a4.z, a4.w);
      p.z = pack_u(b4.x, b4.y); p.w = pack_u(b4.z, b4.w);
      WL[(((w << 1) | i) * 8 + kc) * 64 + l] = p;
    }

  // ---- state init --------------------------------------------------------
  float c_reg = 0.f;
  if (t < 256) c_reg = c0[dir * HH + t];
  if (t < 128)
    h16u[t] = pack_u(h0[dir * HH + 2 * t], h0[dir * HH + 2 * t + 1]);

  float4 zx = make_float4(0.f, 0.f, 0.f, 0.f);
  if (t < 256) {
    const int trow0 = dir ? (LL - 1) : 0;
    zx = *reinterpret_cast<const float4*>(Z + (size_t)trow0 * NGATE + 4 * t);
  }
  __syncthreads();

  for (int s = 0; s < LL; ++s) {
    const int par = s & 1;
    // prefetch next step's Zx (one float4, hides under matvec)
    float4 nzx = make_float4(0.f, 0.f, 0.f, 0.f);
    if (t < 256 && s + 1 < LL) {
      const int trow = dir ? (LL - 2 - s) : (s + 1);
      nzx = *reinterpret_cast<const float4*>(Z + (size_t)trow * NGATE + 4 * t);
    }

    const uint4* hq = reinterpret_cast<const uint4*>(&h16u[par << 7]);

    // ---- LDS-streamed MFMA pass (kc outer, 2 accs live) ------------------
    v4f accL0 = {0.f,0.f,0.f,0.f}, accL1 = {0.f,0.f,0.f,0.f};
    {
      const int b0 = (((w << 1) | 0) * 8) * 64 + l;
      const int b1 = (((w << 1) | 1) * 8) * 64 + l;
#pragma unroll
      for (int kc = 0; kc < 8; ++kc) {
        const v8h ah = __builtin_bit_cast(v8h, hq[(kc << 2) + lq]);
        const uint4 w0 = WL[b0 + (kc << 6)];
        const uint4 w1 = WL[b1 + (kc << 6)];
        accL0 = __builtin_amdgcn_mfma_f32_16x16x32_f16(ah, __builtin_bit_cast(v8h, w0), accL0, 0, 0, 0);
        accL1 = __builtin_amdgcn_mfma_f32_16x16x32_f16(ah, __builtin_bit_cast(v8h, w1), accL1, 0, 0, 0);
      }
    }

    // ---- VALU fdot2 part: rows rq+128j (j=0..2), k in [64kq,64kq+64) -----
    float a0 = 0.f, a1 = 0.f, a2 = 0.f;
#pragma unroll
    for (int i = 0; i < 8; ++i) {
      const uint4 hv = hq[(kq << 3) + i];
      const v2h hx = u2h(hv.x), hy = u2h(hv.y), hz = u2h(hv.z), hw = u2h(hv.w);
      a0 = __builtin_amdgcn_fdot2(wv[0][4*i+0], hx, a0, false);
      a1 = __builtin_amdgcn_fdot2(wv[1][4*i+0], hx, a1, false);
      a2 = __builtin_amdgcn_fdot2(wv[2][4*i+0], hx, a2, false);
      a0 = __builtin_amdgcn_fdot2(wv[0][4*i+1], hy, a0, false);
      a1 = __builtin_amdgcn_fdot2(wv[1][4*i+1], hy, a1, false);
      a2 = __builtin_amdgcn_fdot2(wv[2][4*i+1], hy, a2, false);
      a0 = __builtin_amdgcn_fdot2(wv[0][4*i+2], hz, a0, false);
      a1 = __builtin_amdgcn_fdot2(wv[1][4*i+2], hz, a1, false);
      a2 = __builtin_amdgcn_fdot2(wv[2][4*i+2], hz, a2, false);
      a0 = __builtin_amdgcn_fdot2(wv[0][4*i+3], hw, a0, false);
      a1 = __builtin_amdgcn_fdot2(wv[1][4*i+3], hw, a1, false);
      a2 = __builtin_amdgcn_fdot2(wv[2][4*i+3], hw, a2, false);
    }
    a0 += dpp_f<0xB1>(a0); a0 += dpp_f<0x4E>(a0);
    a1 += dpp_f<0xB1>(a1); a1 += dpp_f<0x4E>(a1);
    a2 += dpp_f<0xB1>(a2); a2 += dpp_f<0x4E>(a2);
    if (kq == 0) {
      // n=rq -> (u=rq,g=0); n=rq+128 -> (u=rq+128,g=0); n=rq+256 -> (u=rq,g=1)
      zbuf4[(rq << 2)] = a0;
      zbuf4[((rq + 128) << 2)] = a1;
      zbuf4[(rq << 2) + 1] = a2;
    }

    // ---- reg-resident MFMA pass (kc outer, 3 accs live) ------------------
    v4f accR0 = {0.f,0.f,0.f,0.f}, accR1 = {0.f,0.f,0.f,0.f}, accR2 = {0.f,0.f,0.f,0.f};
#pragma unroll
    for (int kc = 0; kc < 8; ++kc) {
      const v8h ah = __builtin_bit_cast(v8h, hq[(kc << 2) + lq]);
      accR0 = __builtin_amdgcn_mfma_f32_16x16x32_f16(ah, bfr[0 * 8 + kc], accR0, 0, 0, 0);
      accR1 = __builtin_amdgcn_mfma_f32_16x16x32_f16(ah, bfr[1 * 8 + kc], accR1, 0, 0, 0);
      accR2 = __builtin_amdgcn_mfma_f32_16x16x32_f16(ah, bfr[2 * 8 + kc], accR2, 0, 0, 0);
    }

    // ---- z writes (rows replicated -> acc[0] valid; lq==0 lanes) ---------
    if (lq == 0) {
      {
        const int n = ((24 + 3 * w + 0) << 4) + lcol;
        zbuf4[((n & 255) << 2) | (n >> 8)] = accR0[0];
      }
      {
        const int n = ((24 + 3 * w + 1) << 4) + lcol;
        zbuf4[((n & 255) << 2) | (n >> 8)] = accR1[0];
      }
      {
        const int n = ((24 + 3 * w + 2) << 4) + lcol;
        zbuf4[((n & 255) << 2) | (n >> 8)] = accR2[0];
      }
      {
        const int n = ((48 + 2 * w + 0) << 4) + lcol;
        zbuf4[((n & 255) << 2) | (n >> 8)] = accL0[0];
      }
      {
        const int n = ((48 + 2 * w + 1) << 4) + lcol;
        zbuf4[((n & 255) << 2) | (n >> 8)] = accL1[0];
      }
    }
    __syncthreads();

    // ---- gate phase (unit u = t, threads 0..255) -------------------------
    if (t < 256) {
      const float4 zv = *reinterpret_cast<const float4*>(&zbuf4[t << 2]);
      const float z0 = zx.x + zv.x;
      const float z1 = zx.y + zv.y;
      const float z2 = zx.z + zv.z;
      const float z3 = zx.w + zv.w;
      const float ig = fsigmoid(z0);
      const float fg = fsigmoid(z1);
      const float gg = ftanh(z2);
      const float og = fsigmoid(z3);
      c_reg = fg * c_reg + ig * gg;
      const float hval = og * ftanh(c_reg);
      const int trow = dir ? (LL - 1 - s) : s;
      Hall[(size_t)trow * HH + t] = hval;
      const float hnb = dpp_f<0xB1>(hval);   // neighbor (t^1) within quad
      if ((t & 1) == 0)
        h16u[((par ^ 1) << 7) + (t >> 1)] = pack_u(hval, hnb);
    }
    __syncthreads();
    zx = nzx;
  }
}

// ---------------------------------------------------------------------------
// Kernel 4: feats
// ---------------------------------------------------------------------------
__global__ __launch_bounds__(256) void feats_gemm(
    const float* __restrict__ HALL, const float* __restrict__ Wout,
    const float* __restrict__ bout, float* __restrict__ FE) {
  __shared__ float Wl[16][516];
  const int t = threadIdx.x;
  for (int i = t; i < 16 * 512; i += 256) Wl[i >> 9][i & 511] = Wout[i];
  __syncthreads();
  const int row = blockIdx.x * 16 + (t >> 4);
  const int j = t & 15;
  const float* hf = HALL + (size_t)row * HH;
  const float* hb = HALL + (size_t)LL * HH + (size_t)row * HH;
  float acc = bout[j];
  for (int k = 0; k < HH; k += 4) {
    const float4 a = *reinterpret_cast<const float4*>(hf + k);
    const float4 wa = *reinterpret_cast<const float4*>(&Wl[j][k]);
    acc += a.x * wa.x + a.y * wa.y + a.z * wa.z + a.w * wa.w;
    const float4 b2 = *reinterpret_cast<const float4*>(hb + k);
    const float4 wb = *reinterpret_cast<const float4*>(&Wl[j][256 + k]);
    acc += b2.x * wb.x + b2.y * wb.y + b2.z * wb.z + b2.w * wb.w;
  }
  FE[(size_t)row * TT + j] = acc;
}

// ---------------------------------------------------------------------------
// Kernel 5: Viterbi (unchanged)
// ---------------------------------------------------------------------------
__global__ __launch_bounds__(1024) void viterbi(
    const float* __restrict__ FE, const float* __restrict__ trans,
    float* __restrict__ out) {
  __shared__ unsigned char bp8[LL * TT];
  __shared__ unsigned char xc[64 * 16];
  __shared__ unsigned char entry[64];
  __shared__ int sbest;
  const int t = threadIdx.x;

  if (t < 64) {
    const int n = t >> 2, pg = t & 3;
    const float tr0 = trans[n * 16 + (pg << 2) + 0];
    const float tr1 = trans[n * 16 + (pg << 2) + 1];
    const float tr2 = trans[n * 16 + (pg << 2) + 2];
    const float tr3 = trans[n * 16 + (pg << 2) + 3];
    float fvp0 = ((pg << 2) + 0 == 14) ? 0.f : NEGV;
    float fvp1 = ((pg << 2) + 1 == 14) ? 0.f : NEGV;
    float fvp2 = ((pg << 2) + 2 == 14) ? 0.f : NEGV;
    float fvp3 = ((pg << 2) + 3 == 14) ? 0.f : NEGV;

    auto step = [&](int s, float feat) {
      float bv = fvp0 + tr0; int bi = (pg << 2);
      float c;
      c = fvp1 + tr1; if (c > bv) { bv = c; bi = (pg << 2) + 1; }
      c = fvp2 + tr2; if (c > bv) { bv = c; bi = (pg << 2) + 2; }
      c = fvp3 + tr3; if (c > bv) { bv = c; bi = (pg << 2) + 3; }
      float pv = dpp_f<0xB1>(bv); int pi = dpp_i<0xB1>(bi);
      if (pv > bv || (pv == bv && pi < bi)) { bv = pv; bi = pi; }
      pv = dpp_f<0x4E>(bv); pi = dpp_i<0x4E>(bi);
      if (pv > bv || (pv == bv && pi < bi)) { bv = pv; bi = pi; }
      if (pg == 0) bp8[(s << 4) + n] = (unsigned char)bi;
      const float fvn = bv + feat;
      fvp0 = bperm_f((pg << 4) + 0,  fvn);
      fvp1 = bperm_f((pg << 4) + 4,  fvn);
      fvp2 = bperm_f((pg << 4) + 8,  fvn);
      fvp3 = bperm_f((pg << 4) + 12, fvn);
    };

    float fb0 = FE[(0 << 4) + n], fb1 = FE[(1 << 4) + n];
    float fb2 = FE[(2 << 4) + n], fb3 = FE[(3 << 4) + n];
    for (int s = 0; s < LL; s += 4) {
      step(s + 0, fb0); fb0 = (s + 4 < LL) ? FE[((s + 4) << 4) + n] : 0.f;
      step(s + 1, fb1); fb1 = (s + 5 < LL) ? FE[((s + 5) << 4) + n] : 0.f;
      step(s + 2, fb2); fb2 = (s + 6 < LL) ? FE[((s + 6) << 4) + n] : 0.f;
      step(s + 3, fb3); fb3 = (s + 7 < LL) ? FE[((s + 7) << 4) + n] : 0.f;
    }

    const float tt0 = trans[240 + (pg << 2) + 0];
    const float tt1 = trans[240 + (pg << 2) + 1];
    const float tt2 = trans[240 + (pg << 2) + 2];
    const float tt3 = trans[240 + (pg << 2) + 3];
    float bv = fvp0 + tt0; int bi = (pg << 2);
    float c;
    c = fvp1 + tt1; if (c > bv) { bv = c; bi = (pg << 2) + 1; }
    c = fvp2 + tt2; if (c > bv) { bv = c; bi = (pg << 2) + 2; }
    c = fvp3 + tt3; if (c > bv) { bv = c; bi = (pg << 2) + 3; }
    float pv = dpp_f<0xB1>(bv); int pi = dpp_i<0xB1>(bi);
    if (pv > bv || (pv == bv && pi < bi)) { bv = pv; bi = pi; }
    pv = dpp_f<0x4E>(bv); pi = dpp_i<0x4E>(bi);
    if (pv > bv || (pv == bv && pi < bi)) { bv = pv; bi = pi; }
    if (t == 0) { out[0] = bv; sbest = bi; }
  }
  __syncthreads();

  {
    const int c = t >> 4, e = t & 15;
    int tag = e;
#pragma unroll 1
    for (int i = 63; i >= 0; --i) tag = bp8[(((c << 6) + i) << 4) + tag];
    xc[(c << 4) + e] = (unsigned char)tag;
  }
  __syncthreads();
  if (t == 0) {
    int carry = sbest;
#pragma unroll 1
    for (int c = 63; c >= 0; --c) {
      entry[c] = (unsigned char)carry;
      carry = xc[(c << 4) + carry];
    }
  }
  __syncthreads();
  if (t < 64) {
    const int c = t;
    int tag = entry[c];
#pragma unroll 1
    for (int i = 63; i >= 0; --i) {
      const int s = (c << 6) + i;
      out[1 + s] = (float)tag;
      tag = bp8[(s << 4) + tag];
    }
  }
}

// ---------------------------------------------------------------------------
extern "C" void kernel_launch(void* const* d_in, const int* in_sizes, int n_in,
                              void* d_out, int out_size, void* d_ws, size_t ws_size,
                              hipStream_t stream) {
  const int*   sent = (const int*)d_in[0];
  const float* emb  = (const float*)d_in[1];
  const float* wihf = (const float*)d_in[2];
  const float* whhf = (const float*)d_in[3];
  const float* bf   = (const float*)d_in[4];
  const float* wihb = (const float*)d_in[5];
  const float* whhb = (const float*)d_in[6];
  const float* bb   = (const float*)d_in[7];
  const float* wout = (const float*)d_in[8];
  const float* bout = (const float*)d_in[9];
  const float* trans= (const float*)d_in[10];
  const float* h0   = (const float*)d_in[11];
  const float* c0   = (const float*)d_in[12];
  float* out = (float*)d_out;
  char* ws = (char*)d_ws;

  float* X    = (float*)(ws + OFF_X);
  float* ZX   = (float*)(ws + OFF_ZX);
  float* HALL = (float*)(ws + OFF_HALL);
  float* FE   = (float*)(ws + OFF_FE);

  gather_x<<<(LL * (EE / 4) + 255) / 256, 256, 0, stream>>>(sent, emb, X);
  input_gemm<<<dim3(16, 64, 2), 256, 0, stream>>>(X, wihf, bf, wihb, bb, ZX);
  recurrence<<<2, 512, 0, stream>>>(whhf, whhb, h0, c0, ZX, HALL);
  feats_gemm<<<LL / 16, 256, 0, stream>>>(HALL, wout, bout, FE);
  viterbi<<<1, 1024, 0, stream>>>(FE, trans, out);
}

// Round 6
// 7587.737 us; speedup vs baseline: 3.0928x; 3.0928x over previous
//
#include <hip/hip_runtime.h>
#include <math.h>
#include <stdint.h>

// Problem constants
constexpr int LL = 4096;   // seq len
constexpr int EE = 300;    // embedding dim
constexpr int HH = 256;    // per-direction hidden (H2)
constexpr int NGATE = 1024;// 4*HH
constexpr int TT = 16;     // tagset
constexpr float NEGV = -10000.0f;

typedef _Float16 v2h __attribute__((ext_vector_type(2)));
typedef _Float16 v8h __attribute__((ext_vector_type(8)));
typedef float v4f __attribute__((ext_vector_type(4)));

// Workspace layout (byte offsets)
constexpr size_t OFF_SLOT = 0;                              // LLC slots (4 KB used)
constexpr size_t OFF_MIR  = 8192;                           // L2 mirror (4 KB used)
constexpr size_t OFF_X    = 16384;
constexpr size_t OFF_ZX   = OFF_X    + (size_t)LL*EE*4;     // 2*L*1024 f32
constexpr size_t OFF_HALL = OFF_ZX   + (size_t)2*LL*NGATE*4;// 2*L*256 f32
constexpr size_t OFF_FE   = OFF_HALL + (size_t)2*LL*HH*4;   // L*16 f32

__device__ __forceinline__ v2h pack_h2(float x, float y) {
  return __builtin_bit_cast(v2h, __builtin_amdgcn_cvt_pkrtz(x, y));
}
__device__ __forceinline__ unsigned pack_u(float x, float y) {
  return __builtin_bit_cast(unsigned, __builtin_amdgcn_cvt_pkrtz(x, y));
}
__device__ __forceinline__ v8h make_v8h(v2h a, v2h b, v2h c, v2h d) {
  union { v2h p[4]; v8h v; } u; u.p[0]=a; u.p[1]=b; u.p[2]=c; u.p[3]=d; return u.v;
}

__device__ __forceinline__ float fsigmoid(float x) {
  return __builtin_amdgcn_rcpf(1.f + __expf(-x));
}
__device__ __forceinline__ float ftanh(float x) {
  return 1.f - 2.f * __builtin_amdgcn_rcpf(1.f + __expf(2.f * x));
}

template <int CTRL>
__device__ __forceinline__ int dpp_i(int v) {
  return __builtin_amdgcn_mov_dpp(v, CTRL, 0xF, 0xF, true);
}
template <int CTRL>
__device__ __forceinline__ float dpp_f(float v) {
  return __int_as_float(__builtin_amdgcn_mov_dpp(__float_as_int(v), CTRL, 0xF, 0xF, true));
}
__device__ __forceinline__ float bperm_f(int lane, float v) {
  return __int_as_float(__builtin_amdgcn_ds_bpermute(lane << 2, __float_as_int(v)));
}

// L2-path load: bypass L1 (sc0), served by this XCD's L2.
__device__ __forceinline__ unsigned long long l2_load_u64(const unsigned long long* p) {
  unsigned long long v;
  asm volatile("global_load_dwordx2 %0, %1, off sc0\n\t"
               "s_waitcnt vmcnt(0)"
               : "=v"(v) : "v"(p) : "memory");
  return v;
}
// Dual probe: mirror (L2, sc0) + slot (LLC, sc0 sc1) concurrently, one wait.
__device__ __forceinline__ void dual_probe(const unsigned long long* mp,
                                           const unsigned long long* ap,
                                           unsigned long long& vm,
                                           unsigned long long& va) {
  asm volatile("global_load_dwordx2 %0, %2, off sc0\n\t"
               "global_load_dwordx2 %1, %3, off sc0 sc1\n\t"
               "s_waitcnt vmcnt(0)"
               : "=v"(vm), "=v"(va) : "v"(mp), "v"(ap) : "memory");
}

// ---------------------------------------------------------------------------
// Kernel 1: embedding gather
// ---------------------------------------------------------------------------
__global__ void gather_x(const int* __restrict__ sent, const float* __restrict__ emb,
                         float* __restrict__ X) {
  const int i = blockIdx.x * blockDim.x + threadIdx.x;
  const int total = LL * (EE / 4);
  if (i >= total) return;
  const int row = i / (EE / 4), c4 = i % (EE / 4);
  const int v = sent[row];
  reinterpret_cast<float4*>(X)[(size_t)row * (EE / 4) + c4] =
      reinterpret_cast<const float4*>(emb + (size_t)v * EE)[c4];
}

// ---------------------------------------------------------------------------
// Kernel 2: input GEMM, GATE-TRANSPOSED store: Zx[t][unit*4+gate]
// ---------------------------------------------------------------------------
__global__ __launch_bounds__(256) void input_gemm(
    const float* __restrict__ X, const float* __restrict__ w_f,
    const float* __restrict__ b_f, const float* __restrict__ w_b,
    const float* __restrict__ b_b, float* __restrict__ ZX) {
  const int dir = blockIdx.z;
  const float* __restrict__ W  = dir ? w_b : w_f;
  const float* __restrict__ Bv = dir ? b_b : b_f;
  float* __restrict__ Z = ZX + (size_t)dir * LL * NGATE;
  __shared__ float As[32][68];
  __shared__ float Bs[32][68];
  const int m0 = blockIdx.y * 64, n0 = blockIdx.x * 64;
  const int t = threadIdx.x;
  const int tx = t & 15, ty = t >> 4;
  float acc[4][4] = {};
  for (int k0 = 0; k0 < EE; k0 += 32) {
#pragma unroll
    for (int r = 0; r < 2; ++r) {
      const int idx = t + r * 256;
      const int row = idx >> 3;
      const int kk4 = (idx & 7) << 2;
      const int k = k0 + kk4;
      float4 va = make_float4(0.f, 0.f, 0.f, 0.f), vb = va;
      if (k < EE) {
        va = *reinterpret_cast<const float4*>(X + (size_t)(m0 + row) * EE + k);
        vb = *reinterpret_cast<const float4*>(W + (size_t)(n0 + row) * EE + k);
      }
      As[kk4 + 0][row] = va.x; As[kk4 + 1][row] = va.y;
      As[kk4 + 2][row] = va.z; As[kk4 + 3][row] = va.w;
      Bs[kk4 + 0][row] = vb.x; Bs[kk4 + 1][row] = vb.y;
      Bs[kk4 + 2][row] = vb.z; Bs[kk4 + 3][row] = vb.w;
    }
    __syncthreads();
    const int kmax = (EE - k0 < 32) ? (EE - k0) : 32;
    for (int k = 0; k < kmax; ++k) {
      const float4 av = *reinterpret_cast<const float4*>(&As[k][ty << 2]);
      const float4 bv = *reinterpret_cast<const float4*>(&Bs[k][tx << 2]);
      acc[0][0] += av.x * bv.x; acc[0][1] += av.x * bv.y; acc[0][2] += av.x * bv.z; acc[0][3] += av.x * bv.w;
      acc[1][0] += av.y * bv.x; acc[1][1] += av.y * bv.y; acc[1][2] += av.y * bv.z; acc[1][3] += av.y * bv.w;
      acc[2][0] += av.z * bv.x; acc[2][1] += av.z * bv.y; acc[2][2] += av.z * bv.z; acc[2][3] += av.z * bv.w;
      acc[3][0] += av.w * bv.x; acc[3][1] += av.w * bv.y; acc[3][2] += av.w * bv.z; acc[3][3] += av.w * bv.w;
    }
    __syncthreads();
  }
#pragma unroll
  for (int i = 0; i < 4; ++i)
#pragma unroll
    for (int j = 0; j < 4; ++j) {
      const int m = m0 + (ty << 2) + i, n = n0 + (tx << 2) + j;
      Z[(size_t)m * NGATE + (((n & 255) << 2) | (n >> 8))] = acc[i][j] + Bv[n];
    }
}

// ---------------------------------------------------------------------------
// Kernel 3: persistent bidirectional LSTM recurrence — TWO WGs per direction.
//
// R5 post-mortem: single-CU hybrid spilled to scratch (~250 unified regs
// demanded; 13k cy/step all-idle). R2 (all-MFMA 1 WG/dir) is clean but
// pipe-bound: 512 tile-chunks x 4.85 cy = 2483 cy/CU/step. Fix the RESOURCE:
// split each direction over 2 CUs -> 256 tile-chunks/CU (1242 cy), and each
// WG's 256 KB weight half fits ENTIRELY in 32 v8h frags = 128 regs/thread
// (~174 total demand — no LDS stream, no spill pressure).
//
// Cross-WG h-exchange (64 u64/step each way), R0-proven machinery:
//  * tag = step+1 (1-based: zero/poison never matches), parity double-buffer
//    (lockstep proof: WG step s needs peer's s-1 => overwrite-safe)
//  * producer: agent-scope u64 stores to MIR (L2) + SLOT (LLC)
//  * consumer: l2 probe then dual L2+LLC probe
//  * k-split overlap: own-half k MFMAs (~621 cy) issue BEFORE the poll, so
//    the L2/LLC round trip hides under the matrix pipe.
// Pair co-location: blocks {0,8}=dir0, {1,9}=dir1 (blockIdx%8 -> XCD
// heuristic); correctness never depends on it (LLC probe is the fallback).
// ---------------------------------------------------------------------------
__global__ __launch_bounds__(512) __attribute__((amdgpu_waves_per_eu(2, 2)))
void recurrence(
    const float* __restrict__ whh_f, const float* __restrict__ whh_b,
    const float* __restrict__ h0, const float* __restrict__ c0,
    const float* __restrict__ ZX, float* __restrict__ HALL,
    unsigned long long* __restrict__ SLOT, unsigned long long* __restrict__ MIR) {
  const int b = blockIdx.x;
  const int lane7 = b & 7;
  if (lane7 >= 2) return;                 // inactive placement blocks
  const int dir = lane7;                  // blocks {0,8}: dir0; {1,9}: dir1
  const int p = (b >> 3) & 1;             // half: units [128p, 128p+128)
  const int t = threadIdx.x;
  const int w = t >> 6;                   // wave 0..7
  const int l = t & 63;
  const int lcol = l & 15;
  const int lq = l >> 4;                  // quadrant 0..3
  const float* __restrict__ Whh = dir ? whh_b : whh_f;
  const float* __restrict__ Z = ZX + (size_t)dir * LL * NGATE;
  float* __restrict__ Hall = HALL + (size_t)dir * LL * HH;
  // exchange regions: [dir][half] x [parity 2][64] u64
  unsigned long long* __restrict__ slotP = SLOT + ((dir << 1) | p) * 128;       // mine (write)
  unsigned long long* __restrict__ mirP  = MIR  + ((dir << 1) | p) * 128;
  const unsigned long long* __restrict__ slotX = SLOT + ((dir << 1) | (1 - p)) * 128; // peer (read)
  const unsigned long long* __restrict__ mirX  = MIR  + ((dir << 1) | (1 - p)) * 128;

  __shared__ __align__(16) float zbuf4[512];        // [u_local][gate]
  __shared__ __align__(16) unsigned h16u[2 * 128];  // packed f16 h, parity dbuf

  // ---- preamble: whole weight half -> 32 v8h frags (128 regs) ------------
  // tile T = w*4+j : gate g=T>>3, unit-tile ut=T&7; n = g*256 + 128p + ut*16 + lcol
  // slot j*8 + half*4 + i <- k-chunk kc = 4*(half?1-p:p) + i  (own first)
  v8h bf[32];
#pragma unroll
  for (int j = 0; j < 4; ++j) {
    const int T = (w << 2) + j;
    const int n = ((T >> 3) << 8) + (p << 7) + ((T & 7) << 4) + lcol;
    const float* nrow = Whh + (size_t)n * HH;
#pragma unroll
    for (int hf = 0; hf < 2; ++hf) {
#pragma unroll
      for (int i = 0; i < 4; ++i) {
        const int kc = ((hf ? (1 - p) : p) << 2) + i;
        const float* wp = nrow + (kc << 5) + (lq << 3);
        const float4 a4 = *reinterpret_cast<const float4*>(wp);
        const float4 b4 = *reinterpret_cast<const float4*>(wp + 4);
        bf[(j << 3) + (hf << 2) + i] =
            make_v8h(pack_h2(a4.x, a4.y), pack_h2(a4.z, a4.w),
                     pack_h2(b4.x, b4.y), pack_h2(b4.z, b4.w));
      }
    }
  }

  // ---- state init --------------------------------------------------------
  float c_reg = 0.f;
  if (t < 128) c_reg = c0[dir * HH + (p << 7) + t];
  if (t < 128)  // full h0 (both halves) into parity-0 LDS buffer
    h16u[t] = pack_u(h0[dir * HH + 2 * t], h0[dir * HH + 2 * t + 1]);
  if (t < 64) { // publish own half, tag 1, parity 0
    const unsigned hp = pack_u(h0[dir * HH + (p << 7) + 2 * t],
                               h0[dir * HH + (p << 7) + 2 * t + 1]);
    const unsigned long long v = (1ULL << 32) | (unsigned long long)hp;
    __hip_atomic_store(&mirP[t],  v, __ATOMIC_RELAXED, __HIP_MEMORY_SCOPE_AGENT);
    __hip_atomic_store(&slotP[t], v, __ATOMIC_RELAXED, __HIP_MEMORY_SCOPE_AGENT);
  }

  float4 zx = make_float4(0.f, 0.f, 0.f, 0.f);
  if (t < 128) {
    const int trow0 = dir ? (LL - 1) : 0;
    zx = *reinterpret_cast<const float4*>(Z + (size_t)trow0 * NGATE + (((p << 7) + t) << 2));
  }
  __syncthreads();

  const int po = p << 2;          // own kc base
  const int pf = (1 - p) << 2;    // foreign kc base

  for (int s = 0; s < LL; ++s) {
    const int par = s & 1;
    const int npar = par ^ 1;
    // prefetch next step's Zx early (hides under matvec)
    float4 nzx = make_float4(0.f, 0.f, 0.f, 0.f);
    if (t < 128 && s + 1 < LL) {
      const int trow = dir ? (LL - 2 - s) : (s + 1);
      nzx = *reinterpret_cast<const float4*>(Z + (size_t)trow * NGATE + (((p << 7) + t) << 2));
    }

    const uint4* hq = reinterpret_cast<const uint4*>(&h16u[par << 7]);

    // ---- own-half k MFMAs (no foreign dependency) ------------------------
    v4f acc0 = {0.f,0.f,0.f,0.f}, acc1 = {0.f,0.f,0.f,0.f};
    v4f acc2 = {0.f,0.f,0.f,0.f}, acc3 = {0.f,0.f,0.f,0.f};
#pragma unroll
    for (int i = 0; i < 4; ++i) {
      const v8h ah = __builtin_bit_cast(v8h, hq[((po + i) << 2) + lq]);
      acc0 = __builtin_amdgcn_mfma_f32_16x16x32_f16(ah, bf[0 * 8 + i], acc0, 0, 0, 0);
      acc1 = __builtin_amdgcn_mfma_f32_16x16x32_f16(ah, bf[1 * 8 + i], acc1, 0, 0, 0);
      acc2 = __builtin_amdgcn_mfma_f32_16x16x32_f16(ah, bf[2 * 8 + i], acc2, 0, 0, 0);
      acc3 = __builtin_amdgcn_mfma_f32_16x16x32_f16(ah, bf[3 * 8 + i], acc3, 0, 0, 0);
    }

    // ---- poll foreign half (tag s+1, parity s&1) -------------------------
    if (t < 64) {
      const unsigned tagw = (unsigned)(s + 1);
      const int pi = par * 64 + t;
      const unsigned long long* mp = &mirX[pi];
      const unsigned long long* ap = &slotX[pi];
      unsigned long long v;
      for (;;) {
        v = l2_load_u64(mp);
        if ((unsigned)(v >> 32) == tagw) break;
        unsigned long long vm, va;
        dual_probe(mp, ap, vm, va);
        if ((unsigned)(vm >> 32) == tagw) { v = vm; break; }
        if ((unsigned)(va >> 32) == tagw) { v = va; break; }
      }
      h16u[(par << 7) + ((1 - p) << 6) + t] = (unsigned)v;
    }
    __syncthreads();

    // ---- foreign-half k MFMAs --------------------------------------------
#pragma unroll
    for (int i = 0; i < 4; ++i) {
      const v8h ah = __builtin_bit_cast(v8h, hq[((pf + i) << 2) + lq]);
      acc0 = __builtin_amdgcn_mfma_f32_16x16x32_f16(ah, bf[0 * 8 + 4 + i], acc0, 0, 0, 0);
      acc1 = __builtin_amdgcn_mfma_f32_16x16x32_f16(ah, bf[1 * 8 + 4 + i], acc1, 0, 0, 0);
      acc2 = __builtin_amdgcn_mfma_f32_16x16x32_f16(ah, bf[2 * 8 + 4 + i], acc2, 0, 0, 0);
      acc3 = __builtin_amdgcn_mfma_f32_16x16x32_f16(ah, bf[3 * 8 + 4 + i], acc3, 0, 0, 0);
    }

    // ---- z writes (A rows replicated -> acc[0]; lq==0 lanes) -------------
    if (lq == 0) {
#pragma unroll
      for (int j = 0; j < 4; ++j) {
        const int T = (w << 2) + j;
        const float zv = (j == 0) ? acc0[0] : (j == 1) ? acc1[0]
                        : (j == 2) ? acc2[0] : acc3[0];
        zbuf4[(((((T & 7) << 4) + lcol)) << 2) + (T >> 3)] = zv;
      }
    }
    __syncthreads();

    // ---- gate phase (u_local = t, threads 0..127) ------------------------
    if (t < 128) {
      const float4 zv = *reinterpret_cast<const float4*>(&zbuf4[t << 2]);
      const float z0 = zx.x + zv.x;
      const float z1 = zx.y + zv.y;
      const float z2 = zx.z + zv.z;
      const float z3 = zx.w + zv.w;
      const float ig = fsigmoid(z0);
      const float fg = fsigmoid(z1);
      const float gg = ftanh(z2);
      const float og = fsigmoid(z3);
      c_reg = fg * c_reg + ig * gg;
      const float hval = og * ftanh(c_reg);
      const int trow = dir ? (LL - 1 - s) : s;
      Hall[(size_t)trow * HH + (p << 7) + t] = hval;
      const float hnb = dpp_f<0xB1>(hval);   // neighbor t^1 in quad
      if ((t & 1) == 0) {
        const unsigned hp = pack_u(hval, hnb);
        h16u[(npar << 7) + (p << 6) + (t >> 1)] = hp;
        // publish for peer's step s+1: tag s+2, parity (s+1)&1
        const unsigned long long v =
            ((unsigned long long)(unsigned)(s + 2) << 32) | (unsigned long long)hp;
        const int pi = npar * 64 + (t >> 1);
        __hip_atomic_store(&mirP[pi],  v, __ATOMIC_RELAXED, __HIP_MEMORY_SCOPE_AGENT);
        __hip_atomic_store(&slotP[pi], v, __ATOMIC_RELAXED, __HIP_MEMORY_SCOPE_AGENT);
      }
    }
    __syncthreads();
    zx = nzx;
  }
}

// ---------------------------------------------------------------------------
// Kernel 4: feats
// ---------------------------------------------------------------------------
__global__ __launch_bounds__(256) void feats_gemm(
    const float* __restrict__ HALL, const float* __restrict__ Wout,
    const float* __restrict__ bout, float* __restrict__ FE) {
  __shared__ float Wl[16][516];
  const int t = threadIdx.x;
  for (int i = t; i < 16 * 512; i += 256) Wl[i >> 9][i & 511] = Wout[i];
  __syncthreads();
  const int row = blockIdx.x * 16 + (t >> 4);
  const int j = t & 15;
  const float* hf = HALL + (size_t)row * HH;
  const float* hb = HALL + (size_t)LL * HH + (size_t)row * HH;
  float acc = bout[j];
  for (int k = 0; k < HH; k += 4) {
    const float4 a = *reinterpret_cast<const float4*>(hf + k);
    const float4 wa = *reinterpret_cast<const float4*>(&Wl[j][k]);
    acc += a.x * wa.x + a.y * wa.y + a.z * wa.z + a.w * wa.w;
    const float4 b2 = *reinterpret_cast<const float4*>(hb + k);
    const float4 wb = *reinterpret_cast<const float4*>(&Wl[j][256 + k]);
    acc += b2.x * wb.x + b2.y * wb.y + b2.z * wb.z + b2.w * wb.w;
  }
  FE[(size_t)row * TT + j] = acc;
}

// ---------------------------------------------------------------------------
// Kernel 5: Viterbi (unchanged)
// ---------------------------------------------------------------------------
__global__ __launch_bounds__(1024) void viterbi(
    const float* __restrict__ FE, const float* __restrict__ trans,
    float* __restrict__ out) {
  __shared__ unsigned char bp8[LL * TT];
  __shared__ unsigned char xc[64 * 16];
  __shared__ unsigned char entry[64];
  __shared__ int sbest;
  const int t = threadIdx.x;

  if (t < 64) {
    const int n = t >> 2, pg = t & 3;
    const float tr0 = trans[n * 16 + (pg << 2) + 0];
    const float tr1 = trans[n * 16 + (pg << 2) + 1];
    const float tr2 = trans[n * 16 + (pg << 2) + 2];
    const float tr3 = trans[n * 16 + (pg << 2) + 3];
    float fvp0 = ((pg << 2) + 0 == 14) ? 0.f : NEGV;
    float fvp1 = ((pg << 2) + 1 == 14) ? 0.f : NEGV;
    float fvp2 = ((pg << 2) + 2 == 14) ? 0.f : NEGV;
    float fvp3 = ((pg << 2) + 3 == 14) ? 0.f : NEGV;

    auto step = [&](int s, float feat) {
      float bv = fvp0 + tr0; int bi = (pg << 2);
      float c;
      c = fvp1 + tr1; if (c > bv) { bv = c; bi = (pg << 2) + 1; }
      c = fvp2 + tr2; if (c > bv) { bv = c; bi = (pg << 2) + 2; }
      c = fvp3 + tr3; if (c > bv) { bv = c; bi = (pg << 2) + 3; }
      float pv = dpp_f<0xB1>(bv); int pi = dpp_i<0xB1>(bi);
      if (pv > bv || (pv == bv && pi < bi)) { bv = pv; bi = pi; }
      pv = dpp_f<0x4E>(bv); pi = dpp_i<0x4E>(bi);
      if (pv > bv || (pv == bv && pi < bi)) { bv = pv; bi = pi; }
      if (pg == 0) bp8[(s << 4) + n] = (unsigned char)bi;
      const float fvn = bv + feat;
      fvp0 = bperm_f((pg << 4) + 0,  fvn);
      fvp1 = bperm_f((pg << 4) + 4,  fvn);
      fvp2 = bperm_f((pg << 4) + 8,  fvn);
      fvp3 = bperm_f((pg << 4) + 12, fvn);
    };

    float fb0 = FE[(0 << 4) + n], fb1 = FE[(1 << 4) + n];
    float fb2 = FE[(2 << 4) + n], fb3 = FE[(3 << 4) + n];
    for (int s = 0; s < LL; s += 4) {
      step(s + 0, fb0); fb0 = (s + 4 < LL) ? FE[((s + 4) << 4) + n] : 0.f;
      step(s + 1, fb1); fb1 = (s + 5 < LL) ? FE[((s + 5) << 4) + n] : 0.f;
      step(s + 2, fb2); fb2 = (s + 6 < LL) ? FE[((s + 6) << 4) + n] : 0.f;
      step(s + 3, fb3); fb3 = (s + 7 < LL) ? FE[((s + 7) << 4) + n] : 0.f;
    }

    const float tt0 = trans[240 + (pg << 2) + 0];
    const float tt1 = trans[240 + (pg << 2) + 1];
    const float tt2 = trans[240 + (pg << 2) + 2];
    const float tt3 = trans[240 + (pg << 2) + 3];
    float bv = fvp0 + tt0; int bi = (pg << 2);
    float c;
    c = fvp1 + tt1; if (c > bv) { bv = c; bi = (pg << 2) + 1; }
    c = fvp2 + tt2; if (c > bv) { bv = c; bi = (pg << 2) + 2; }
    c = fvp3 + tt3; if (c > bv) { bv = c; bi = (pg << 2) + 3; }
    float pv = dpp_f<0xB1>(bv); int pi = dpp_i<0xB1>(bi);
    if (pv > bv || (pv == bv && pi < bi)) { bv = pv; bi = pi; }
    pv = dpp_f<0x4E>(bv); pi = dpp_i<0x4E>(bi);
    if (pv > bv || (pv == bv && pi < bi)) { bv = pv; bi = pi; }
    if (t == 0) { out[0] = bv; sbest = bi; }
  }
  __syncthreads();

  {
    const int c = t >> 4, e = t & 15;
    int tag = e;
#pragma unroll 1
    for (int i = 63; i >= 0; --i) tag = bp8[(((c << 6) + i) << 4) + tag];
    xc[(c << 4) + e] = (unsigned char)tag;
  }
  __syncthreads();
  if (t == 0) {
    int carry = sbest;
#pragma unroll 1
    for (int c = 63; c >= 0; --c) {
      entry[c] = (unsigned char)carry;
      carry = xc[(c << 4) + carry];
    }
  }
  __syncthreads();
  if (t < 64) {
    const int c = t;
    int tag = entry[c];
#pragma unroll 1
    for (int i = 63; i >= 0; --i) {
      const int s = (c << 6) + i;
      out[1 + s] = (float)tag;
      tag = bp8[(s << 4) + tag];
    }
  }
}

// ---------------------------------------------------------------------------
extern "C" void kernel_launch(void* const* d_in, const int* in_sizes, int n_in,
                              void* d_out, int out_size, void* d_ws, size_t ws_size,
                              hipStream_t stream) {
  const int*   sent = (const int*)d_in[0];
  const float* emb  = (const float*)d_in[1];
  const float* wihf = (const float*)d_in[2];
  const float* whhf = (const float*)d_in[3];
  const float* bf   = (const float*)d_in[4];
  const float* wihb = (const float*)d_in[5];
  const float* whhb = (const float*)d_in[6];
  const float* bb   = (const float*)d_in[7];
  const float* wout = (const float*)d_in[8];
  const float* bout = (const float*)d_in[9];
  const float* trans= (const float*)d_in[10];
  const float* h0   = (const float*)d_in[11];
  const float* c0   = (const float*)d_in[12];
  float* out = (float*)d_out;
  char* ws = (char*)d_ws;

  unsigned long long* SLOT = (unsigned long long*)(ws + OFF_SLOT);
  unsigned long long* MIR  = (unsigned long long*)(ws + OFF_MIR);
  float* X    = (float*)(ws + OFF_X);
  float* ZX   = (float*)(ws + OFF_ZX);
  float* HALL = (float*)(ws + OFF_HALL);
  float* FE   = (float*)(ws + OFF_FE);

  gather_x<<<(LL * (EE / 4) + 255) / 256, 256, 0, stream>>>(sent, emb, X);
  input_gemm<<<dim3(16, 64, 2), 256, 0, stream>>>(X, wihf, bf, wihb, bb, ZX);
  recurrence<<<16, 512, 0, stream>>>(whhf, whhb, h0, c0, ZX, HALL, SLOT, MIR);
  feats_gemm<<<LL / 16, 256, 0, stream>>>(HALL, wout, bout, FE);
  viterbi<<<1, 1024, 0, stream>>>(FE, trans, out);
}